// Round 5
// baseline (342.569 us; speedup 1.0000x reference)
//
#include <hip/hip_runtime.h>
#include <cstdint>

// B=4, L=2048, H=512, HEADS=8, D=64.
// Only the DIAGONAL of softmax(scores) is consumed:
//   diag_i = exp(s_ii) / sum_j exp(s_ij),
//   s_ij = q_i.k_j + q_i.Wp[2047+j-i] + Wp_b[2047+j-i]
// Logits in log2 units (q pre-scaled by log2e/8, Wp_b by log2e) -> one
// v_exp_f32 per element.
//
// Round-5 note: R3/R4 precomputed a banded P but only for 2 of 16 bh per
// pass — the rest read workspace poison (~0) and still passed because pos
// is numerically tiny here. This version computes pos EXACTLY, in-kernel:
// per wave-iter two 32-col P tiles via MFMA (fp32, same C/D row mapping as
// the score tile), then a ds_bpermute lane-rotation remaps P[row][c] to the
// score element (row, j) with c = 63 + j - row. No LDS tiles, no barrier,
// no OOB, no pos round-trip through memory.

typedef unsigned short u16;
typedef __bf16 bf16x8 __attribute__((ext_vector_type(8)));
typedef float  f32x16 __attribute__((ext_vector_type(16)));
typedef uint32_t __attribute__((address_space(1))) as1_u32;
typedef uint32_t __attribute__((address_space(3))) as3_u32;

__device__ __forceinline__ u16 f2bf(float f) {
  uint32_t x = __float_as_uint(f);
  x += 0x7fffu + ((x >> 16) & 1u);   // RTNE (finite inputs)
  return (u16)(x >> 16);
}
__device__ __forceinline__ float bf2f(u16 u) {
  return __uint_as_float(((uint32_t)u) << 16);
}
__device__ __forceinline__ void gl_lds16(const void* g, void* l) {
  __builtin_amdgcn_global_load_lds((const as1_u32*)g, (as3_u32*)l, 16, 0, 0);
}

// ---------------------------------------------------------------------------
// Prep: fp32 -> bf16 for q/k/v inputs, Wq/Wk/Wv/Wo, Wp (padded to 4352 rows),
// plus wpb2[4352] = Wp_b * log2e (fp32, zero-padded).
// ---------------------------------------------------------------------------
__global__ __launch_bounds__(256) void prep_kernel(
    const float* __restrict__ qin, const float* __restrict__ kin, const float* __restrict__ vin,
    const float* __restrict__ wq,  const float* __restrict__ wk,  const float* __restrict__ wv,
    const float* __restrict__ wo,  const float* __restrict__ wp,  const float* __restrict__ wpb,
    u16* __restrict__ xq, u16* __restrict__ xk, u16* __restrict__ xv,
    u16* __restrict__ bwq, u16* __restrict__ bwk, u16* __restrict__ bwv,
    u16* __restrict__ bwo, u16* __restrict__ bwp, float* __restrict__ wpb2) {
  long u = (long)blockIdx.x * 256 + threadIdx.x;
  const float* src; u16* dst; long off;
  if      (u < 524288L)  { src = qin; dst = xq;  off = u; }
  else if (u < 1048576L) { src = kin; dst = xk;  off = u - 524288L; }
  else if (u < 1572864L) { src = vin; dst = xv;  off = u - 1048576L; }
  else if (u < 1605632L) { src = wq;  dst = bwq; off = u - 1572864L; }
  else if (u < 1638400L) { src = wk;  dst = bwk; off = u - 1605632L; }
  else if (u < 1671168L) { src = wv;  dst = bwv; off = u - 1638400L; }
  else if (u < 1703936L) { src = wo;  dst = bwo; off = u - 1671168L; }
  else if (u < 1736696L) { src = wp;  dst = bwp; off = u - 1703936L; }
  else if (u < 1738752L) {  // zero-fill Wp pad rows 4095..4351
    long o = (u - 1736696L) * 8 + 262080L;
    uint4 z = {0u, 0u, 0u, 0u};
    *(uint4*)(bwp + o) = z;
    return;
  } else if (u < 1739296L) {  // wpb2 = wpb * log2e, padded to 4352
    long b0 = (u - 1738752L) * 8;
#pragma unroll
    for (int e = 0; e < 8; ++e) {
      long gi = b0 + e;
      wpb2[gi] = (gi < 4095L) ? wpb[gi] * 1.4426950408889634f : 0.f;
    }
    return;
  } else return;
  const float4* s4 = (const float4*)(src + off * 8);
  float4 a = s4[0], b = s4[1];
  uint32_t p0 = (uint32_t)f2bf(a.x) | ((uint32_t)f2bf(a.y) << 16);
  uint32_t p1 = (uint32_t)f2bf(a.z) | ((uint32_t)f2bf(a.w) << 16);
  uint32_t p2 = (uint32_t)f2bf(b.x) | ((uint32_t)f2bf(b.y) << 16);
  uint32_t p3 = (uint32_t)f2bf(b.z) | ((uint32_t)f2bf(b.w) << 16);
  uint4 o = {p0, p1, p2, p3};
  *(uint4*)(dst + off * 8) = o;
}

// ---------------------------------------------------------------------------
// gemm_bt: C = (A @ W^T + bias) * scale.  A: 8192x512 bf16, W: 512x512 bf16.
// 128x128 tile, 4 waves, 32x32x16 MFMA, BK=32, global_load_lds staging.
// mode 0: bf16 out in (b,h,l,d); mode 1: fp32 out row-major.
// ---------------------------------------------------------------------------
__global__ __launch_bounds__(256) void gemm_bt(
    const u16* __restrict__ A, const u16* __restrict__ W, const float* __restrict__ bias,
    u16* __restrict__ obf, float* __restrict__ ofp, float scale, int mode) {
  __shared__ u16 Al[128 * 32];
  __shared__ u16 Bl[128 * 32];
  const int tid = threadIdx.x;
  const int lane = tid & 63, w = tid >> 6;
  const int wi = w >> 1, wj = w & 1;
  const int m0 = (blockIdx.x >> 2) * 128, n0 = (blockIdx.x & 3) * 128;

  f32x16 acc[2][2];
#pragma unroll
  for (int i = 0; i < 2; ++i)
#pragma unroll
    for (int j = 0; j < 2; ++j)
#pragma unroll
      for (int r = 0; r < 16; ++r) acc[i][j][r] = 0.f;

  for (int kb = 0; kb < 16; ++kb) {
#pragma unroll
    for (int c = 0; c < 2; ++c) {
      int s = c * 256 + w * 64 + lane;
      int r = s >> 2, ch = s & 3;
      int gch = ch ^ ((r >> 1) & 3);
      gl_lds16(A + (long)(m0 + r) * 512 + kb * 32 + gch * 8, (char*)Al + (c * 256 + w * 64) * 16);
      gl_lds16(W + (long)(n0 + r) * 512 + kb * 32 + gch * 8, (char*)Bl + (c * 256 + w * 64) * 16);
    }
    __syncthreads();
    bf16x8 af[2][2], bfr[2][2];
#pragma unroll
    for (int mt = 0; mt < 2; ++mt)
#pragma unroll
      for (int ks = 0; ks < 2; ++ks) {
        int r = 64 * wi + 32 * mt + (lane & 31);
        int ch = 2 * ks + (lane >> 5);
        af[mt][ks] = *(const bf16x8*)((char*)Al + (r * 4 + (ch ^ ((r >> 1) & 3))) * 16);
      }
#pragma unroll
    for (int nt = 0; nt < 2; ++nt)
#pragma unroll
      for (int ks = 0; ks < 2; ++ks) {
        int r = 64 * wj + 32 * nt + (lane & 31);
        int ch = 2 * ks + (lane >> 5);
        bfr[nt][ks] = *(const bf16x8*)((char*)Bl + (r * 4 + (ch ^ ((r >> 1) & 3))) * 16);
      }
#pragma unroll
    for (int mt = 0; mt < 2; ++mt)
#pragma unroll
      for (int nt = 0; nt < 2; ++nt)
#pragma unroll
        for (int ks = 0; ks < 2; ++ks)
          acc[mt][nt] = __builtin_amdgcn_mfma_f32_32x32x16_bf16(af[mt][ks], bfr[nt][ks],
                                                                acc[mt][nt], 0, 0, 0);
    __syncthreads();
  }
#pragma unroll
  for (int nt = 0; nt < 2; ++nt) {
    int n = n0 + 64 * wj + 32 * nt + (lane & 31);
    float bv = bias[n];
#pragma unroll
    for (int mt = 0; mt < 2; ++mt) {
#pragma unroll
      for (int r = 0; r < 16; ++r) {
        int row = m0 + 64 * wi + 32 * mt + (r & 3) + 8 * (r >> 2) + 4 * (lane >> 5);
        float val = (acc[mt][nt][r] + bv) * scale;
        if (mode == 0) {
          int b = row >> 11, l = row & 2047, h = n >> 6, d = n & 63;
          obf[(((long)(b * 8 + h)) * 2048 + l) * 64 + d] = f2bf(val);
        } else {
          ofp[(long)row * 512 + n] = val;
        }
      }
    }
  }
}

// ---------------------------------------------------------------------------
// Fused Q/K/V projection: 768 blocks (3 matrices x 256 tiles).
// q gets scale log2e/8 baked in (log2-unit logits downstream).
// ---------------------------------------------------------------------------
__global__ __launch_bounds__(256) void qkv_gemm(
    const u16* __restrict__ xq, const u16* __restrict__ xk, const u16* __restrict__ xv,
    const u16* __restrict__ wqp, const u16* __restrict__ wkp, const u16* __restrict__ wvp,
    const float* __restrict__ bq, const float* __restrict__ bk, const float* __restrict__ bv,
    u16* __restrict__ oq, u16* __restrict__ ok, u16* __restrict__ ov) {
  __shared__ u16 Al[128 * 32];
  __shared__ u16 Bl[128 * 32];
  const int mat = blockIdx.x >> 8;
  const int tile = blockIdx.x & 255;
  const u16* A = (mat == 0) ? xq : (mat == 1) ? xk : xv;
  const u16* W = (mat == 0) ? wqp : (mat == 1) ? wkp : wvp;
  const float* bias = (mat == 0) ? bq : (mat == 1) ? bk : bv;
  u16* obf = (mat == 0) ? oq : (mat == 1) ? ok : ov;
  const float scale = (mat == 0) ? 0.18033688f : 1.0f;  // log2e/8 for q

  const int tid = threadIdx.x;
  const int lane = tid & 63, w = tid >> 6;
  const int wi = w >> 1, wj = w & 1;
  const int m0 = (tile >> 2) * 128, n0 = (tile & 3) * 128;

  f32x16 acc[2][2];
#pragma unroll
  for (int i = 0; i < 2; ++i)
#pragma unroll
    for (int j = 0; j < 2; ++j)
#pragma unroll
      for (int r = 0; r < 16; ++r) acc[i][j][r] = 0.f;

  for (int kb = 0; kb < 16; ++kb) {
#pragma unroll
    for (int c = 0; c < 2; ++c) {
      int s = c * 256 + w * 64 + lane;
      int r = s >> 2, ch = s & 3;
      int gch = ch ^ ((r >> 1) & 3);
      gl_lds16(A + (long)(m0 + r) * 512 + kb * 32 + gch * 8, (char*)Al + (c * 256 + w * 64) * 16);
      gl_lds16(W + (long)(n0 + r) * 512 + kb * 32 + gch * 8, (char*)Bl + (c * 256 + w * 64) * 16);
    }
    __syncthreads();
    bf16x8 af[2][2], bfr[2][2];
#pragma unroll
    for (int mt = 0; mt < 2; ++mt)
#pragma unroll
      for (int ks = 0; ks < 2; ++ks) {
        int r = 64 * wi + 32 * mt + (lane & 31);
        int ch = 2 * ks + (lane >> 5);
        af[mt][ks] = *(const bf16x8*)((char*)Al + (r * 4 + (ch ^ ((r >> 1) & 3))) * 16);
      }
#pragma unroll
    for (int nt = 0; nt < 2; ++nt)
#pragma unroll
      for (int ks = 0; ks < 2; ++ks) {
        int r = 64 * wj + 32 * nt + (lane & 31);
        int ch = 2 * ks + (lane >> 5);
        bfr[nt][ks] = *(const bf16x8*)((char*)Bl + (r * 4 + (ch ^ ((r >> 1) & 3))) * 16);
      }
#pragma unroll
    for (int mt = 0; mt < 2; ++mt)
#pragma unroll
      for (int nt = 0; nt < 2; ++nt)
#pragma unroll
        for (int ks = 0; ks < 2; ++ks)
          acc[mt][nt] = __builtin_amdgcn_mfma_f32_32x32x16_bf16(af[mt][ks], bfr[nt][ks],
                                                                acc[mt][nt], 0, 0, 0);
    __syncthreads();
  }
#pragma unroll
  for (int nt = 0; nt < 2; ++nt) {
    int n = n0 + 64 * wj + 32 * nt + (lane & 31);
    float bvv = bias[n];
#pragma unroll
    for (int mt = 0; mt < 2; ++mt) {
#pragma unroll
      for (int r = 0; r < 16; ++r) {
        int row = m0 + 64 * wi + 32 * mt + (r & 3) + 8 * (r >> 2) + 4 * (lane >> 5);
        float val = (acc[mt][nt][r] + bvv) * scale;
        int b = row >> 11, l = row & 2047, h = n >> 6, d = n & 63;
        obf[(((long)(b * 8 + h)) * 2048 + l) * 64 + d] = f2bf(val);
      }
    }
  }
}

// ---------------------------------------------------------------------------
// Attention: one block per (bh, 32-row i-tile); grid 2048, 4 waves, no
// barrier / no LDS in the j-loop.  Each iter covers 128 j (32 per wave).
// Per wave-iter: 4 score MFMA + 8 pos MFMA (two 32-col P tiles, fp32),
// bias add, ds_bpermute lane-rotation remap of P into score layout,
// 16x (add + v_exp_f32) accumulate.
//   pos element (row, j):  c = 63 + j - row maps to Wp row W0 + rel,
//   W0 = 2016 - I0 + Jw,  rel = 31 + l31 - row  in [0,62];
//   tile t = rel>>5, source lane = 32*lh + (rel&31)  (same reg r: score and
//   P share the C/D row mapping lrr+4*lh).
// XCD swizzle: bh = (bi&7) + 8*((bi>>3)&3) keeps each bh's K on one XCD L2.
// ---------------------------------------------------------------------------
__global__ __launch_bounds__(256, 3) void attn_kernel(
    const u16* __restrict__ qw, const u16* __restrict__ kw, const u16* __restrict__ vw,
    const u16* __restrict__ wpw, const float* __restrict__ wpb2, u16* __restrict__ outp) {
  __shared__ float rssum[32 * 4];
  __shared__ float sdiag[32];
  __shared__ float attw[32];

  const int tid = threadIdx.x, lane = tid & 63, w = tid >> 6;
  const int bi = blockIdx.x;
  const int bh = (bi & 7) + 8 * ((bi >> 3) & 3);
  const int it32 = bi >> 5;            // 0..63
  const int I0 = it32 * 32;
  const int l31 = lane & 31, lh = lane >> 5;
  const int row_off = 4 * lh;          // row = lrr + 4*lh
  const u16* qb = qw + (long)bh * 131072;
  const u16* kb = kw + (long)bh * 131072;
  const u16* vb = vw + (long)bh * 131072;

  // A-frags: Q rows I0 + l31, K=64 (pre-scaled by log2e/8)
  bf16x8 aq[4];
  {
    const u16* p = qb + (long)(I0 + l31) * 64 + lh * 8;
#pragma unroll
    for (int kk = 0; kk < 4; ++kk) aq[kk] = *(const bf16x8*)(p + kk * 16);
  }

  float rsum[16];
#pragma unroll
  for (int r = 0; r < 16; ++r) rsum[r] = 0.f;

  const int vv = l31 + 31 - row_off;        // rel = vv - lrr
  const int lane32b = (lane & 32) << 2;     // bpermute byte-addr half offset
  const int diag_jt = I0 >> 7, diag_w = (I0 >> 5) & 3;

  for (int jt = 0; jt < 16; ++jt) {
    const int Jw = 128 * jt + 32 * w;
    // K B-frags: rows Jw + l31
    bf16x8 kf[4];
    {
      const u16* p = kb + (long)(Jw + l31) * 64 + lh * 8;
#pragma unroll
      for (int kk = 0; kk < 4; ++kk) kf[kk] = *(const bf16x8*)(p + kk * 16);
    }
    // Two P tiles: Wp rows W0+l31 and W0+32+l31 (W0+rel <= 4094; row 4095 is
    // the zero pad, touched only by never-selected pcol 31 of tile 1)
    const int W0 = 2016 - I0 + Jw;
    f32x16 P0, P1, accS;
#pragma unroll
    for (int r = 0; r < 16; ++r) { P0[r] = 0.f; P1[r] = 0.f; accS[r] = 0.f; }
    {
      const u16* bp0 = wpw + (long)(W0 + l31) * 64 + lh * 8;
#pragma unroll
      for (int kk = 0; kk < 4; ++kk) {
        bf16x8 b0 = *(const bf16x8*)(bp0 + kk * 16);
        P0 = __builtin_amdgcn_mfma_f32_32x32x16_bf16(aq[kk], b0, P0, 0, 0, 0);
      }
      const u16* bp1 = bp0 + 32 * 64;
#pragma unroll
      for (int kk = 0; kk < 4; ++kk) {
        bf16x8 b1 = *(const bf16x8*)(bp1 + kk * 16);
        P1 = __builtin_amdgcn_mfma_f32_32x32x16_bf16(aq[kk], b1, P1, 0, 0, 0);
      }
      const float bv0 = wpb2[W0 + l31];
      const float bv1 = wpb2[W0 + 32 + l31];
#pragma unroll
      for (int r = 0; r < 16; ++r) { P0[r] += bv0; P1[r] += bv1; }
    }
    // scores
#pragma unroll
    for (int kk = 0; kk < 4; ++kk)
      accS = __builtin_amdgcn_mfma_f32_32x32x16_bf16(aq[kk], kf[kk], accS, 0, 0, 0);
    // remap P into score layout; combine; accumulate 2^s
    const bool dt = (jt == diag_jt) && (w == diag_w);
#pragma unroll
    for (int r = 0; r < 16; ++r) {
      const int lrr = (r & 3) + 8 * (r >> 2);
      int rel = vv - lrr;                        // [0, 62]
      int srcb = ((rel & 31) << 2) | lane32b;
      float p0 = __uint_as_float(
          (uint32_t)__builtin_amdgcn_ds_bpermute(srcb, (int)__float_as_uint(P0[r])));
      float p1 = __uint_as_float(
          (uint32_t)__builtin_amdgcn_ds_bpermute(srcb, (int)__float_as_uint(P1[r])));
      float p = (rel & 32) ? p1 : p0;
      float s = accS[r] + p;
      rsum[r] += __builtin_amdgcn_exp2f(s);
      if (dt && l31 == lrr + row_off) sdiag[lrr + row_off] = s;
    }
  }

  // reduce over the 32 j-lanes of each row
#pragma unroll
  for (int r = 0; r < 16; ++r) {
    float v = rsum[r];
    v += __shfl_xor(v, 1);
    v += __shfl_xor(v, 2);
    v += __shfl_xor(v, 4);
    v += __shfl_xor(v, 8);
    v += __shfl_xor(v, 16);
    rsum[r] = v;
  }
  if (l31 == 0) {
#pragma unroll
    for (int r = 0; r < 16; ++r) {
      int row = (r & 3) + 8 * (r >> 2) + row_off;
      rssum[row * 4 + w] = rsum[r];
    }
  }
  __syncthreads();
  if (tid < 32) {
    float S = rssum[tid * 4] + rssum[tid * 4 + 1] + rssum[tid * 4 + 2] + rssum[tid * 4 + 3];
    attw[tid] = __builtin_amdgcn_exp2f(sdiag[tid]) / S;
  }
  __syncthreads();
  // out_pre[b*2048 + i][h*64 + d] = diag * v   (bf16); 32 rows x 64 d
  {
    int r = tid >> 3, dd = (tid & 7) * 8;
    float a = attw[r];
    int b = bh >> 3, h = bh & 7;
    const u16* vp = vb + (long)(I0 + r) * 64 + dd;
    u16* op = outp + ((long)(b * 2048 + I0 + r)) * 512 + h * 64 + dd;
    uint4 v0 = *(const uint4*)vp;
    uint32_t vin[4] = {v0.x, v0.y, v0.z, v0.w};
    uint32_t vout[4];
#pragma unroll
    for (int e = 0; e < 4; ++e) {
      float lo = bf2f((u16)(vin[e] & 0xffffu)) * a;
      float hi = bf2f((u16)(vin[e] >> 16)) * a;
      vout[e] = (uint32_t)f2bf(lo) | ((uint32_t)f2bf(hi) << 16);
    }
    uint4 o0 = {vout[0], vout[1], vout[2], vout[3]};
    *(uint4*)op = o0;
  }
}

// ---------------------------------------------------------------------------
extern "C" void kernel_launch(void* const* d_in, const int* in_sizes, int n_in,
                              void* d_out, int out_size, void* d_ws, size_t ws_size,
                              hipStream_t stream) {
  (void)in_sizes; (void)n_in; (void)out_size; (void)ws_size;
  const float* q_in = (const float*)d_in[0];
  const float* k_in = (const float*)d_in[1];
  const float* v_in = (const float*)d_in[2];
  const float* Wq_w = (const float*)d_in[3];
  const float* Wq_b = (const float*)d_in[4];
  const float* Wk_w = (const float*)d_in[5];
  const float* Wk_b = (const float*)d_in[6];
  const float* Wv_w = (const float*)d_in[7];
  const float* Wv_b = (const float*)d_in[8];
  const float* Wo_w = (const float*)d_in[9];
  const float* Wo_b = (const float*)d_in[10];
  const float* Wp_w = (const float*)d_in[11];
  const float* Wp_b = (const float*)d_in[12];

  // Workspace (peak 60.4 MB, within the proven-safe region):
  char* ws = (char*)d_ws;
  u16*   wq    = (u16*)(ws + 0);
  u16*   wk    = (u16*)(ws + 524288);
  u16*   wv    = (u16*)(ws + 1048576);
  u16*   wo    = (u16*)(ws + 1572864);
  u16*   wp    = (u16*)(ws + 2097152);    // 4352x64 bf16 = 557,056
  float* wpb2  = (float*)(ws + 2654208);  // 4352 fp32 -> ends 2,671,616
  u16*   q_ws  = (u16*)(ws + 2672640);    // 8 MB (b,h,l,d), log2e/8-scaled
  u16*   k_ws  = (u16*)(ws + 11061248);   // 8 MB
  u16*   v_ws  = (u16*)(ws + 19449856);   // 8 MB
  u16*   opre  = (u16*)(ws + 27838464);   // 8 MB (b*l, h*d)
  u16*   xq    = (u16*)(ws + 36227072);   // transient (dead after qkv_gemm)
  u16*   xk    = (u16*)(ws + 44615680);
  u16*   xv    = (u16*)(ws + 53004288);   // ends 61,392,896

  prep_kernel<<<6795, 256, 0, stream>>>(q_in, k_in, v_in, Wq_w, Wk_w, Wv_w, Wo_w, Wp_w, Wp_b,
                                        xq, xk, xv, wq, wk, wv, wo, wp, wpb2);
  qkv_gemm<<<768, 256, 0, stream>>>(xq, xk, xv, wq, wk, wv, Wq_b, Wk_b, Wv_b,
                                    q_ws, k_ws, v_ws);
  attn_kernel<<<2048, 256, 0, stream>>>(q_ws, k_ws, v_ws, wp, wpb2, opre);
  gemm_bt<<<256, 256, 0, stream>>>(opre, wo, Wo_b, nullptr, (float*)d_out, 1.0f, 1);
}

// Round 7
// 331.040 us; speedup vs baseline: 1.0348x; 1.0348x over previous
//
#include <hip/hip_runtime.h>
#include <cstdint>

// B=4, L=2048, H=512, HEADS=8, D=64.
// Only the DIAGONAL of softmax(scores) is consumed:
//   diag_i = exp(s_ii) / sum_j exp(s_ij),
//   s_ij = q_i.k_j + q_i.Wp[2047+j-i] + Wp_b[2047+j-i]
// Logits in log2 units (q pre-scaled by log2e/8, Wp_b by log2e) -> one
// v_exp_f32 per element.  pos is computed EXACTLY in-kernel: per wave-iter
// two 32-col P tiles via MFMA, packed bf16 into a PER-WAVE LDS scratch,
// then 16 ds_read_u16 Toeplitz gathers remap P[row][c] (c = 31+j-row) into
// the score C-layout.
//
// ROUND-7 FIX (R6 produced NaN): the scratch handoff is CROSS-LANE LDS
// communication within one wave. LLVM's per-workitem memory model cannot
// see cross-lane aliasing, so without an ordering point it may hoist the
// gather reads above the writes -> reads of uninitialized LDS (can be NaN
// bit patterns). __builtin_amdgcn_wave_barrier() (zero runtime cost) pins
// the order at both handoff points; scratch is also zero-initialized once.

typedef unsigned short u16;
typedef __bf16 bf16x8 __attribute__((ext_vector_type(8)));
typedef float  f32x16 __attribute__((ext_vector_type(16)));
typedef uint32_t __attribute__((address_space(1))) as1_u32;
typedef uint32_t __attribute__((address_space(3))) as3_u32;

__device__ __forceinline__ u16 f2bf(float f) {
  uint32_t x = __float_as_uint(f);
  x += 0x7fffu + ((x >> 16) & 1u);   // RTNE (finite inputs)
  return (u16)(x >> 16);
}
__device__ __forceinline__ float bf2f(u16 u) {
  return __uint_as_float(((uint32_t)u) << 16);
}
__device__ __forceinline__ void gl_lds16(const void* g, void* l) {
  __builtin_amdgcn_global_load_lds((const as1_u32*)g, (as3_u32*)l, 16, 0, 0);
}

// ---------------------------------------------------------------------------
// Prep: fp32 -> bf16 for q/k/v inputs, Wq/Wk/Wv/Wo, Wp (padded to 4352 rows),
// plus wpb2[4352] = Wp_b * log2e (fp32, zero-padded).
// ---------------------------------------------------------------------------
__global__ __launch_bounds__(256) void prep_kernel(
    const float* __restrict__ qin, const float* __restrict__ kin, const float* __restrict__ vin,
    const float* __restrict__ wq,  const float* __restrict__ wk,  const float* __restrict__ wv,
    const float* __restrict__ wo,  const float* __restrict__ wp,  const float* __restrict__ wpb,
    u16* __restrict__ xq, u16* __restrict__ xk, u16* __restrict__ xv,
    u16* __restrict__ bwq, u16* __restrict__ bwk, u16* __restrict__ bwv,
    u16* __restrict__ bwo, u16* __restrict__ bwp, float* __restrict__ wpb2) {
  long u = (long)blockIdx.x * 256 + threadIdx.x;
  const float* src; u16* dst; long off;
  if      (u < 524288L)  { src = qin; dst = xq;  off = u; }
  else if (u < 1048576L) { src = kin; dst = xk;  off = u - 524288L; }
  else if (u < 1572864L) { src = vin; dst = xv;  off = u - 1048576L; }
  else if (u < 1605632L) { src = wq;  dst = bwq; off = u - 1572864L; }
  else if (u < 1638400L) { src = wk;  dst = bwk; off = u - 1605632L; }
  else if (u < 1671168L) { src = wv;  dst = bwv; off = u - 1638400L; }
  else if (u < 1703936L) { src = wo;  dst = bwo; off = u - 1671168L; }
  else if (u < 1736696L) { src = wp;  dst = bwp; off = u - 1703936L; }
  else if (u < 1738752L) {  // zero-fill Wp pad rows 4095..4351
    long o = (u - 1736696L) * 8 + 262080L;
    uint4 z = {0u, 0u, 0u, 0u};
    *(uint4*)(bwp + o) = z;
    return;
  } else if (u < 1739296L) {  // wpb2 = wpb * log2e, padded to 4352
    long b0 = (u - 1738752L) * 8;
#pragma unroll
    for (int e = 0; e < 8; ++e) {
      long gi = b0 + e;
      wpb2[gi] = (gi < 4095L) ? wpb[gi] * 1.4426950408889634f : 0.f;
    }
    return;
  } else return;
  const float4* s4 = (const float4*)(src + off * 8);
  float4 a = s4[0], b = s4[1];
  uint32_t p0 = (uint32_t)f2bf(a.x) | ((uint32_t)f2bf(a.y) << 16);
  uint32_t p1 = (uint32_t)f2bf(a.z) | ((uint32_t)f2bf(a.w) << 16);
  uint32_t p2 = (uint32_t)f2bf(b.x) | ((uint32_t)f2bf(b.y) << 16);
  uint32_t p3 = (uint32_t)f2bf(b.z) | ((uint32_t)f2bf(b.w) << 16);
  uint4 o = {p0, p1, p2, p3};
  *(uint4*)(dst + off * 8) = o;
}

// ---------------------------------------------------------------------------
// gemm_bt: C = (A @ W^T + bias) * scale.  A: 8192x512 bf16, W: 512x512 bf16.
// 128x128 tile, 4 waves, 32x32x16 MFMA, BK=32, global_load_lds staging.
// mode 0: bf16 out in (b,h,l,d); mode 1: fp32 out row-major.
// ---------------------------------------------------------------------------
__global__ __launch_bounds__(256) void gemm_bt(
    const u16* __restrict__ A, const u16* __restrict__ W, const float* __restrict__ bias,
    u16* __restrict__ obf, float* __restrict__ ofp, float scale, int mode) {
  __shared__ u16 Al[128 * 32];
  __shared__ u16 Bl[128 * 32];
  const int tid = threadIdx.x;
  const int lane = tid & 63, w = tid >> 6;
  const int wi = w >> 1, wj = w & 1;
  const int m0 = (blockIdx.x >> 2) * 128, n0 = (blockIdx.x & 3) * 128;

  f32x16 acc[2][2];
#pragma unroll
  for (int i = 0; i < 2; ++i)
#pragma unroll
    for (int j = 0; j < 2; ++j)
#pragma unroll
      for (int r = 0; r < 16; ++r) acc[i][j][r] = 0.f;

  for (int kb = 0; kb < 16; ++kb) {
#pragma unroll
    for (int c = 0; c < 2; ++c) {
      int s = c * 256 + w * 64 + lane;
      int r = s >> 2, ch = s & 3;
      int gch = ch ^ ((r >> 1) & 3);
      gl_lds16(A + (long)(m0 + r) * 512 + kb * 32 + gch * 8, (char*)Al + (c * 256 + w * 64) * 16);
      gl_lds16(W + (long)(n0 + r) * 512 + kb * 32 + gch * 8, (char*)Bl + (c * 256 + w * 64) * 16);
    }
    __syncthreads();
    bf16x8 af[2][2], bfr[2][2];
#pragma unroll
    for (int mt = 0; mt < 2; ++mt)
#pragma unroll
      for (int ks = 0; ks < 2; ++ks) {
        int r = 64 * wi + 32 * mt + (lane & 31);
        int ch = 2 * ks + (lane >> 5);
        af[mt][ks] = *(const bf16x8*)((char*)Al + (r * 4 + (ch ^ ((r >> 1) & 3))) * 16);
      }
#pragma unroll
    for (int nt = 0; nt < 2; ++nt)
#pragma unroll
      for (int ks = 0; ks < 2; ++ks) {
        int r = 64 * wj + 32 * nt + (lane & 31);
        int ch = 2 * ks + (lane >> 5);
        bfr[nt][ks] = *(const bf16x8*)((char*)Bl + (r * 4 + (ch ^ ((r >> 1) & 3))) * 16);
      }
#pragma unroll
    for (int mt = 0; mt < 2; ++mt)
#pragma unroll
      for (int nt = 0; nt < 2; ++nt)
#pragma unroll
        for (int ks = 0; ks < 2; ++ks)
          acc[mt][nt] = __builtin_amdgcn_mfma_f32_32x32x16_bf16(af[mt][ks], bfr[nt][ks],
                                                                acc[mt][nt], 0, 0, 0);
    __syncthreads();
  }
#pragma unroll
  for (int nt = 0; nt < 2; ++nt) {
    int n = n0 + 64 * wj + 32 * nt + (lane & 31);
    float bv = bias[n];
#pragma unroll
    for (int mt = 0; mt < 2; ++mt) {
#pragma unroll
      for (int r = 0; r < 16; ++r) {
        int row = m0 + 64 * wi + 32 * mt + (r & 3) + 8 * (r >> 2) + 4 * (lane >> 5);
        float val = (acc[mt][nt][r] + bv) * scale;
        if (mode == 0) {
          int b = row >> 11, l = row & 2047, h = n >> 6, d = n & 63;
          obf[(((long)(b * 8 + h)) * 2048 + l) * 64 + d] = f2bf(val);
        } else {
          ofp[(long)row * 512 + n] = val;
        }
      }
    }
  }
}

// ---------------------------------------------------------------------------
// Fused Q/K/V projection: 768 blocks (3 matrices x 256 tiles).
// q gets scale log2e/8 baked in (log2-unit logits downstream).
// ---------------------------------------------------------------------------
__global__ __launch_bounds__(256) void qkv_gemm(
    const u16* __restrict__ xq, const u16* __restrict__ xk, const u16* __restrict__ xv,
    const u16* __restrict__ wqp, const u16* __restrict__ wkp, const u16* __restrict__ wvp,
    const float* __restrict__ bq, const float* __restrict__ bk, const float* __restrict__ bv,
    u16* __restrict__ oq, u16* __restrict__ ok, u16* __restrict__ ov) {
  __shared__ u16 Al[128 * 32];
  __shared__ u16 Bl[128 * 32];
  const int mat = blockIdx.x >> 8;
  const int tile = blockIdx.x & 255;
  const u16* A = (mat == 0) ? xq : (mat == 1) ? xk : xv;
  const u16* W = (mat == 0) ? wqp : (mat == 1) ? wkp : wvp;
  const float* bias = (mat == 0) ? bq : (mat == 1) ? bk : bv;
  u16* obf = (mat == 0) ? oq : (mat == 1) ? ok : ov;
  const float scale = (mat == 0) ? 0.18033688f : 1.0f;  // log2e/8 for q

  const int tid = threadIdx.x;
  const int lane = tid & 63, w = tid >> 6;
  const int wi = w >> 1, wj = w & 1;
  const int m0 = (tile >> 2) * 128, n0 = (tile & 3) * 128;

  f32x16 acc[2][2];
#pragma unroll
  for (int i = 0; i < 2; ++i)
#pragma unroll
    for (int j = 0; j < 2; ++j)
#pragma unroll
      for (int r = 0; r < 16; ++r) acc[i][j][r] = 0.f;

  for (int kb = 0; kb < 16; ++kb) {
#pragma unroll
    for (int c = 0; c < 2; ++c) {
      int s = c * 256 + w * 64 + lane;
      int r = s >> 2, ch = s & 3;
      int gch = ch ^ ((r >> 1) & 3);
      gl_lds16(A + (long)(m0 + r) * 512 + kb * 32 + gch * 8, (char*)Al + (c * 256 + w * 64) * 16);
      gl_lds16(W + (long)(n0 + r) * 512 + kb * 32 + gch * 8, (char*)Bl + (c * 256 + w * 64) * 16);
    }
    __syncthreads();
    bf16x8 af[2][2], bfr[2][2];
#pragma unroll
    for (int mt = 0; mt < 2; ++mt)
#pragma unroll
      for (int ks = 0; ks < 2; ++ks) {
        int r = 64 * wi + 32 * mt + (lane & 31);
        int ch = 2 * ks + (lane >> 5);
        af[mt][ks] = *(const bf16x8*)((char*)Al + (r * 4 + (ch ^ ((r >> 1) & 3))) * 16);
      }
#pragma unroll
    for (int nt = 0; nt < 2; ++nt)
#pragma unroll
      for (int ks = 0; ks < 2; ++ks) {
        int r = 64 * wj + 32 * nt + (lane & 31);
        int ch = 2 * ks + (lane >> 5);
        bfr[nt][ks] = *(const bf16x8*)((char*)Bl + (r * 4 + (ch ^ ((r >> 1) & 3))) * 16);
      }
#pragma unroll
    for (int mt = 0; mt < 2; ++mt)
#pragma unroll
      for (int nt = 0; nt < 2; ++nt)
#pragma unroll
        for (int ks = 0; ks < 2; ++ks)
          acc[mt][nt] = __builtin_amdgcn_mfma_f32_32x32x16_bf16(af[mt][ks], bfr[nt][ks],
                                                                acc[mt][nt], 0, 0, 0);
    __syncthreads();
  }
#pragma unroll
  for (int nt = 0; nt < 2; ++nt) {
    int n = n0 + 64 * wj + 32 * nt + (lane & 31);
    float bvv = bias[n];
#pragma unroll
    for (int mt = 0; mt < 2; ++mt) {
#pragma unroll
      for (int r = 0; r < 16; ++r) {
        int row = m0 + 64 * wi + 32 * mt + (r & 3) + 8 * (r >> 2) + 4 * (lane >> 5);
        float val = (acc[mt][nt][r] + bvv) * scale;
        int b = row >> 11, l = row & 2047, h = n >> 6, d = n & 63;
        obf[(((long)(b * 8 + h)) * 2048 + l) * 64 + d] = f2bf(val);
      }
    }
  }
}

// ---------------------------------------------------------------------------
// Attention: one block per (bh, 32-row i-tile); grid 2048, 4 waves.
// Per wave-iter (32 i x 128 j across waves): 12 MFMA (P0, P1, scores),
// P packed bf16 into per-wave LDS scratch; wave_barrier-ordered handoff;
// 16 ds_read_u16 Toeplitz gathers; 16 exp2 accumulate.
// K fragments register-prefetched one iteration ahead; Wp loads are
// L1/L2-hot (557 KB shared) and issued at iteration top.
// Scratch col stride 34 u16 (dword stride 17, coprime 32): <=2-way banks.
// ---------------------------------------------------------------------------
__global__ __launch_bounds__(256, 3) void attn_kernel(
    const u16* __restrict__ qw, const u16* __restrict__ kw, const u16* __restrict__ vw,
    const u16* __restrict__ wpw, const float* __restrict__ wpb2, u16* __restrict__ outp) {
  __shared__ u16 Ps[4][64 * 34];   // per-wave P scratch (4352 B each)
  __shared__ float rssum[32 * 4];
  __shared__ float sdiag[32];
  __shared__ float attw[32];

  const int tid = threadIdx.x, lane = tid & 63, w = tid >> 6;
  const int bi = blockIdx.x;
  const int bh = (bi & 7) + 8 * ((bi >> 3) & 3);
  const int I0 = (bi >> 5) * 32;
  const int l31 = lane & 31, lh = lane >> 5;
  const int row_off = 4 * lh;
  const u16* qb = qw + (long)bh * 131072;
  const u16* kb = kw + (long)bh * 131072;
  const u16* vb = vw + (long)bh * 131072;
  u16* myPs = Ps[w];

  // zero-init this wave's scratch (272 x uint4)
#pragma unroll
  for (int t = 0; t < 5; ++t) {
    int idx = t * 64 + lane;
    if (idx < 272) {
      uint4 z = {0u, 0u, 0u, 0u};
      *(uint4*)(myPs + idx * 8) = z;
    }
  }

  // A-frags: Q rows I0 + l31, K=64 (pre-scaled by log2e/8)
  bf16x8 aq[4];
  {
    const u16* p = qb + (long)(I0 + l31) * 64 + lh * 8;
#pragma unroll
    for (int kk = 0; kk < 4; ++kk) aq[kk] = *(const bf16x8*)(p + kk * 16);
  }

  float rsum[16];
#pragma unroll
  for (int r = 0; r < 16; ++r) rsum[r] = 0.f;

  const int vv = l31 + 31 - row_off;          // rel = vv - lrr, in [0,62]
  const int diag_jt = I0 >> 7, diag_w = (I0 >> 5) & 3;

  // K fragment prefetch for jt=0
  bf16x8 kf[4];
  {
    const u16* p = kb + (long)(32 * w + l31) * 64 + lh * 8;
#pragma unroll
    for (int kk = 0; kk < 4; ++kk) kf[kk] = *(const bf16x8*)(p + kk * 16);
  }

  for (int jt = 0; jt < 16; ++jt) {
    // Wp fragments + biases for THIS iteration (L1/L2-hot window)
    const int W0 = 2016 - I0 + 128 * jt + 32 * w;
    bf16x8 w0f[4], w1f[4];
    {
      const u16* b0 = wpw + (long)(W0 + l31) * 64 + lh * 8;
#pragma unroll
      for (int kk = 0; kk < 4; ++kk) {
        w0f[kk] = *(const bf16x8*)(b0 + kk * 16);
        w1f[kk] = *(const bf16x8*)(b0 + 2048 + kk * 16);
      }
    }
    const float bv0 = wpb2[W0 + l31];
    const float bv1 = wpb2[W0 + 32 + l31];
    // prefetch next iteration's K fragments (wraps at jt=15; harmless)
    bf16x8 kn[4];
    {
      const int Jn = 128 * ((jt + 1) & 15) + 32 * w;
      const u16* p = kb + (long)(Jn + l31) * 64 + lh * 8;
#pragma unroll
      for (int kk = 0; kk < 4; ++kk) kn[kk] = *(const bf16x8*)(p + kk * 16);
    }

    // ordering point: previous iteration's gathers complete before overwrite
    __builtin_amdgcn_wave_barrier();

    // P tile 0 (window cols l31): MFMA, pack bf16, write to scratch
    {
      f32x16 P;
#pragma unroll
      for (int r = 0; r < 16; ++r) P[r] = 0.f;
#pragma unroll
      for (int kk = 0; kk < 4; ++kk)
        P = __builtin_amdgcn_mfma_f32_32x32x16_bf16(aq[kk], w0f[kk], P, 0, 0, 0);
      const int base = l31 * 34 + row_off;
#pragma unroll
      for (int m = 0; m < 8; ++m) {
        const int lrr = 2 * (m & 1) + 8 * (m >> 1);
        uint32_t pk = (uint32_t)f2bf(P[2 * m] + bv0) |
                      ((uint32_t)f2bf(P[2 * m + 1] + bv0) << 16);
        *(uint32_t*)(myPs + base + lrr) = pk;
      }
    }
    // P tile 1 (window cols 32+l31)
    {
      f32x16 P;
#pragma unroll
      for (int r = 0; r < 16; ++r) P[r] = 0.f;
#pragma unroll
      for (int kk = 0; kk < 4; ++kk)
        P = __builtin_amdgcn_mfma_f32_32x32x16_bf16(aq[kk], w1f[kk], P, 0, 0, 0);
      const int base = (32 + l31) * 34 + row_off;
#pragma unroll
      for (int m = 0; m < 8; ++m) {
        const int lrr = 2 * (m & 1) + 8 * (m >> 1);
        uint32_t pk = (uint32_t)f2bf(P[2 * m] + bv1) |
                      ((uint32_t)f2bf(P[2 * m + 1] + bv1) << 16);
        *(uint32_t*)(myPs + base + lrr) = pk;
      }
    }

    // ordering point: writes before gathers (cross-lane, in-order DS pipe)
    __builtin_amdgcn_wave_barrier();

    // scores
    f32x16 accS;
#pragma unroll
    for (int r = 0; r < 16; ++r) accS[r] = 0.f;
#pragma unroll
    for (int kk = 0; kk < 4; ++kk)
      accS = __builtin_amdgcn_mfma_f32_32x32x16_bf16(aq[kk], kf[kk], accS, 0, 0, 0);

    // Toeplitz gathers, combine, accumulate 2^s
    float prr[16];
#pragma unroll
    for (int r = 0; r < 16; ++r) {
      const int lrr = (r & 3) + 8 * (r >> 2);
      prr[r] = bf2f(myPs[(vv - lrr) * 34 + lrr + row_off]);
    }
    const bool dt = (jt == diag_jt) && (w == diag_w);
#pragma unroll
    for (int r = 0; r < 16; ++r) {
      float s = accS[r] + prr[r];
      rsum[r] += __builtin_amdgcn_exp2f(s);
      if (dt) {
        const int lrr = (r & 3) + 8 * (r >> 2);
        if (l31 == lrr + row_off) sdiag[lrr + row_off] = s;
      }
    }
#pragma unroll
    for (int kk = 0; kk < 4; ++kk) kf[kk] = kn[kk];
  }

  // reduce over the 32 j-lanes of each row
#pragma unroll
  for (int r = 0; r < 16; ++r) {
    float v = rsum[r];
    v += __shfl_xor(v, 1);
    v += __shfl_xor(v, 2);
    v += __shfl_xor(v, 4);
    v += __shfl_xor(v, 8);
    v += __shfl_xor(v, 16);
    rsum[r] = v;
  }
  if (l31 == 0) {
#pragma unroll
    for (int r = 0; r < 16; ++r) {
      int row = (r & 3) + 8 * (r >> 2) + row_off;
      rssum[row * 4 + w] = rsum[r];
    }
  }
  __syncthreads();
  if (tid < 32) {
    float S = rssum[tid * 4] + rssum[tid * 4 + 1] + rssum[tid * 4 + 2] + rssum[tid * 4 + 3];
    attw[tid] = __builtin_amdgcn_exp2f(sdiag[tid]) / S;
  }
  __syncthreads();
  // out_pre[b*2048 + i][h*64 + d] = diag * v   (bf16); 32 rows x 64 d
  {
    int r = tid >> 3, dd = (tid & 7) * 8;
    float a = attw[r];
    int b = bh >> 3, h = bh & 7;
    const u16* vp = vb + (long)(I0 + r) * 64 + dd;
    u16* op = outp + ((long)(b * 2048 + I0 + r)) * 512 + h * 64 + dd;
    uint4 v0 = *(const uint4*)vp;
    uint32_t vin[4] = {v0.x, v0.y, v0.z, v0.w};
    uint32_t vout[4];
#pragma unroll
    for (int e = 0; e < 4; ++e) {
      float lo = bf2f((u16)(vin[e] & 0xffffu)) * a;
      float hi = bf2f((u16)(vin[e] >> 16)) * a;
      vout[e] = (uint32_t)f2bf(lo) | ((uint32_t)f2bf(hi) << 16);
    }
    uint4 o0 = {vout[0], vout[1], vout[2], vout[3]};
    *(uint4*)op = o0;
  }
}

// ---------------------------------------------------------------------------
extern "C" void kernel_launch(void* const* d_in, const int* in_sizes, int n_in,
                              void* d_out, int out_size, void* d_ws, size_t ws_size,
                              hipStream_t stream) {
  (void)in_sizes; (void)n_in; (void)out_size; (void)ws_size;
  const float* q_in = (const float*)d_in[0];
  const float* k_in = (const float*)d_in[1];
  const float* v_in = (const float*)d_in[2];
  const float* Wq_w = (const float*)d_in[3];
  const float* Wq_b = (const float*)d_in[4];
  const float* Wk_w = (const float*)d_in[5];
  const float* Wk_b = (const float*)d_in[6];
  const float* Wv_w = (const float*)d_in[7];
  const float* Wv_b = (const float*)d_in[8];
  const float* Wo_w = (const float*)d_in[9];
  const float* Wo_b = (const float*)d_in[10];
  const float* Wp_w = (const float*)d_in[11];
  const float* Wp_b = (const float*)d_in[12];

  // Workspace (peak 61.4 MB, proven safe in R2):
  char* ws = (char*)d_ws;
  u16*   wq    = (u16*)(ws + 0);
  u16*   wk    = (u16*)(ws + 524288);
  u16*   wv    = (u16*)(ws + 1048576);
  u16*   wo    = (u16*)(ws + 1572864);
  u16*   wp    = (u16*)(ws + 2097152);    // 4352x64 bf16 = 557,056
  float* wpb2  = (float*)(ws + 2654208);  // 4352 fp32 -> ends 2,671,616
  u16*   q_ws  = (u16*)(ws + 2672640);    // 8 MB (b,h,l,d), log2e/8-scaled
  u16*   k_ws  = (u16*)(ws + 11061248);   // 8 MB
  u16*   v_ws  = (u16*)(ws + 19449856);   // 8 MB
  u16*   opre  = (u16*)(ws + 27838464);   // 8 MB (b*l, h*d)
  u16*   xq    = (u16*)(ws + 36227072);   // transient (dead after qkv_gemm)
  u16*   xk    = (u16*)(ws + 44615680);
  u16*   xv    = (u16*)(ws + 53004288);   // ends 61,392,896

  prep_kernel<<<6795, 256, 0, stream>>>(q_in, k_in, v_in, Wq_w, Wk_w, Wv_w, Wo_w, Wp_w, Wp_b,
                                        xq, xk, xv, wq, wk, wv, wo, wp, wpb2);
  qkv_gemm<<<768, 256, 0, stream>>>(xq, xk, xv, wq, wk, wv, Wq_b, Wk_b, Wv_b,
                                    q_ws, k_ws, v_ws);
  attn_kernel<<<2048, 256, 0, stream>>>(q_ws, k_ws, v_ws, wp, wpb2, opre);
  gemm_bt<<<256, 256, 0, stream>>>(opre, wo, Wo_b, nullptr, (float*)d_out, 1.0f, 1);
}